// Round 5
// baseline (39.753 us; speedup 1.0000x reference)
//
#include <hip/hip_runtime.h>

#define IMG_H 512
#define IMG_W 512
#define PLANE (IMG_H * IMG_W)
#define NBATCH 64
#define NBINS 256
#define TSTRIP 16
#define WPB 4                                    // waves per block
#define BLOCKS_PER_IMG 8                         // 4 strips each
#define NBLOCKS (BLOCKS_PER_IMG * NBATCH)        // 512

#define GRAY(rr, gg, bb) (0.2989f * (rr) + 0.587f * (gg) + 0.114f * (bb))

// LDS row slots: [2w]=wave w's first row (y0), [2w+1]=wave w's last row (y0+15),
// [8]=block-top halo, [9]=block-bottom halo.
__global__ __launch_bounds__(256) void lbp_strip_kernel(const float* __restrict__ x,
                                                        float* __restrict__ ws) {
    __shared__ float rowbuf[10][IMG_W];
    __shared__ unsigned int lh[NBINS];

    const int tid = threadIdx.x;
    lh[tid] = 0u;

    // XCD swizzle: XCD = blockIdx.x % 8. Group the 8 blocks of one image on one XCD.
    const int lin = blockIdx.x;                  // 0..511
    const int sid = (lin & 7) * (NBLOCKS / 8) + (lin >> 3);
    const int b   = sid >> 3;                    // image 0..63
    const int bg  = sid & 7;                     // strip-group 0..7

    const int wav  = tid >> 6;                   // 0..3
    const int lane = tid & 63;
    const int y0   = (bg * WPB + wav) * TSTRIP;  // wave's first row
    const int by0  = bg * (WPB * TSTRIP);        // block's first row

    const float* rP = x + (size_t)b * 3 * PLANE;
    const float* gP = rP + PLANE;
    const float* bP = rP + 2 * PLANE;
    const int    cx = 8 * lane;

    // ---- gray 8 px of global row gy (clamped) into registers o0,o1 ----
    #define GRAY8(gy_, o0, o1)                                                      \
    do {                                                                            \
        int gy = (gy_);                                                             \
        gy = gy < 0 ? 0 : (gy > IMG_H - 1 ? IMG_H - 1 : gy);                        \
        size_t off = (size_t)gy * IMG_W + cx;                                       \
        float4 ra = *(const float4*)(rP + off), rb = *(const float4*)(rP + off + 4);\
        float4 ga = *(const float4*)(gP + off), gb = *(const float4*)(gP + off + 4);\
        float4 ba = *(const float4*)(bP + off), bb = *(const float4*)(bP + off + 4);\
        o0.x = GRAY(ra.x, ga.x, ba.x); o0.y = GRAY(ra.y, ga.y, ba.y);               \
        o0.z = GRAY(ra.z, ga.z, ba.z); o0.w = GRAY(ra.w, ga.w, ba.w);               \
        o1.x = GRAY(rb.x, gb.x, bb.x); o1.y = GRAY(rb.y, gb.y, bb.y);               \
        o1.z = GRAY(rb.z, gb.z, bb.z); o1.w = GRAY(rb.w, gb.w, bb.w);               \
    } while (0)

    #define FILL(arr, o0, o1)                                                       \
    do {                                                                            \
        arr[1] = o0.x; arr[2] = o0.y; arr[3] = o0.z; arr[4] = o0.w;                 \
        arr[5] = o1.x; arr[6] = o1.y; arr[7] = o1.z; arr[8] = o1.w;                 \
        float lft = __shfl_up(arr[8], 1, 64);                                       \
        float rgt = __shfl_down(arr[1], 1, 64);                                     \
        arr[0] = (lane == 0)  ? arr[1] : lft;                                       \
        arr[9] = (lane == 63) ? arr[8] : rgt;                                       \
    } while (0)

    #define LOADGRAY(arr, gy_)                                                      \
    do { float4 _a, _b; GRAY8(gy_, _a, _b); FILL(arr, _a, _b); } while (0)

    #define LOADLDS(arr, lr)                                                        \
    do {                                                                            \
        float4 _a = *(const float4*)&rowbuf[(lr)][cx];                              \
        float4 _b = *(const float4*)&rowbuf[(lr)][cx + 4];                          \
        FILL(arr, _a, _b);                                                          \
    } while (0)

    // ---- phase 1: stage boundary rows as gray into LDS ----
    {
        float4 a, c;
        GRAY8(y0, a, c);
        *(float4*)&rowbuf[2 * wav][cx] = a; *(float4*)&rowbuf[2 * wav][cx + 4] = c;
        GRAY8(y0 + TSTRIP - 1, a, c);
        *(float4*)&rowbuf[2 * wav + 1][cx] = a; *(float4*)&rowbuf[2 * wav + 1][cx + 4] = c;
        if (wav == 0) {
            GRAY8(by0 - 1, a, c);
            *(float4*)&rowbuf[8][cx] = a; *(float4*)&rowbuf[8][cx + 4] = c;
        } else if (wav == 3) {
            GRAY8(by0 + WPB * TSTRIP, a, c);
            *(float4*)&rowbuf[9][cx] = a; *(float4*)&rowbuf[9][cx + 4] = c;
        }
    }
    __syncthreads();

    // ---- phase 2: 16-row walk; rows 0,15 and neighbors' boundaries from LDS ----
    float t_[10], m_[10], b_[10];

    // OFFSETS = ((-1,-1),(-1,0),(-1,1),(0,1),(1,1),(1,0),(1,-1),(0,-1))
    #define COMPUTE8()                                                             \
    do {                                                                           \
        _Pragma("unroll")                                                          \
        for (int p = 0; p < 8; ++p) {                                              \
            const float ctr = m_[p + 1];                                           \
            unsigned code = 0u;                                                    \
            code |= (t_[p    ] >= ctr) ? 1u   : 0u;                                \
            code |= (t_[p + 1] >= ctr) ? 2u   : 0u;                                \
            code |= (t_[p + 2] >= ctr) ? 4u   : 0u;                                \
            code |= (m_[p + 2] >= ctr) ? 8u   : 0u;                                \
            code |= (b_[p + 2] >= ctr) ? 16u  : 0u;                                \
            code |= (b_[p + 1] >= ctr) ? 32u  : 0u;                                \
            code |= (b_[p    ] >= ctr) ? 64u  : 0u;                                \
            code |= (m_[p    ] >= ctr) ? 128u : 0u;                                \
            atomicAdd(&lh[code], 1u);                                              \
        }                                                                          \
    } while (0)

    #define SHIFT()                                                                \
    do {                                                                           \
        _Pragma("unroll")                                                          \
        for (int k = 0; k < 10; ++k) { t_[k] = m_[k]; m_[k] = b_[k]; }             \
    } while (0)

    LOADLDS(t_, (wav == 0) ? 8 : 2 * (wav - 1) + 1);   // row y0-1
    LOADLDS(m_, 2 * wav);                               // row y0

    #pragma unroll 7
    for (int i = 0; i < TSTRIP - 2; ++i) {              // rows y0+1 .. y0+14 (interior)
        LOADGRAY(b_, y0 + 1 + i);
        COMPUTE8();
        SHIFT();
    }
    LOADLDS(b_, 2 * wav + 1);                           // row y0+15
    COMPUTE8();
    SHIFT();
    LOADLDS(b_, (wav == 3) ? 9 : 2 * (wav + 1));        // row y0+16
    COMPUTE8();

    #undef GRAY8
    #undef FILL
    #undef LOADGRAY
    #undef LOADLDS
    #undef COMPUTE8
    #undef SHIFT

    __syncthreads();
    ws[((size_t)b * BLOCKS_PER_IMG + bg) * NBINS + tid] = (float)lh[tid];
}

// Sum the 8 partials per image, L2-normalize, write output.
__global__ __launch_bounds__(256) void finalize_kernel(const float* __restrict__ ws,
                                                       float* __restrict__ out) {
    const int b = blockIdx.x;
    const int t = threadIdx.x;
    float s = 0.0f;
    #pragma unroll
    for (int k = 0; k < BLOCKS_PER_IMG; ++k)
        s += ws[((size_t)b * BLOCKS_PER_IMG + k) * NBINS + t];
    float ss = s * s;
    #pragma unroll
    for (int o = 32; o > 0; o >>= 1) ss += __shfl_down(ss, o, 64);
    __shared__ float wsum[4];
    if ((t & 63) == 0) wsum[t >> 6] = ss;
    __syncthreads();
    float tot = wsum[0] + wsum[1] + wsum[2] + wsum[3];
    out[b * NBINS + t] = s / (sqrtf(tot) + 1e-6f);
}

extern "C" void kernel_launch(void* const* d_in, const int* in_sizes, int n_in,
                              void* d_out, int out_size, void* d_ws, size_t ws_size,
                              hipStream_t stream) {
    const float* x = (const float*)d_in[0];
    float* out = (float*)d_out;
    float* ws  = (float*)d_ws;   // 64 * 8 * 256 floats = 512 KB partial histograms

    lbp_strip_kernel<<<NBLOCKS, 256, 0, stream>>>(x, ws);
    finalize_kernel<<<NBATCH, 256, 0, stream>>>(ws, out);
}